// Round 11
// baseline (909.544 us; speedup 1.0000x reference)
//
#include <hip/hip_runtime.h>

// MultiFeatureRNNModel: 2-layer tanh RNN (H1=5,H2=3), B=8192, T=512, F=16,
// final-step FC(3->1)+sigmoid.
//
// Round-8 evidence: split-phase scan was latency-bound at ~22% per-CU issue
// with half the chip idle (128 blocks) and an 80MiB xp roundtrip.
// r10 = r9 with transcendentals reverted to the harness-proven spellings
// (__expf/__fdividef; __exp2f collides with glibc math.h here).
//  - 256 blocks x 32 threads -> one wave on every CU,
//    and each wave-load touches 32 cache lines instead of 64.
//  - xproj (80 indep FMAs/step) computed inline: fills issue-stall slots,
//    kills phase-1 kernel + 80MiB write + 84MiB read.
//  - depth-3 prefetch (float4 P[4][4], all static indexing) covers ~900cy
//    HBM latency with ~3 step-times in flight.
// Predict: ~190-240 us kernel, FETCH ~268MB, headline ~440-500.

namespace {
constexpr int kB  = 8192;
constexpr int kT  = 512;
constexpr int kF  = 16;
constexpr int kH1 = 5;
constexpr int kH2 = 3;

__device__ __forceinline__ float fast_tanh(float v) {
    // tanh(v) = 1 - 2/(exp(2v)+1); saturates correctly at +-1.
    float e = __expf(v + v);
    return 1.0f - __fdividef(2.0f, e + 1.0f);
}

struct Weights {
    float w1[kH1][kF];
    float bias1[kH1];
    float whh1[kH1][kH1];
    float wih2[kH2][kH1];
    float whh2[kH2][kH2];
    float bias2[kH2];
    float wfc[kH2];
    float bfc;
};

__device__ __forceinline__ void load_q(const float4* __restrict__ xb, int tl,
                                       float4 (&Q)[4]) {
    const int t = (tl < kT - 1) ? tl : (kT - 1);
#pragma unroll
    for (int q = 0; q < 4; ++q) Q[q] = xb[t * 4 + q];
}

__device__ __forceinline__ void do_step(const float4 (&Q)[4], const Weights& W,
                                        float (&h1)[kH1], float (&h2)[kH2]) {
    const float xv[kF] = {Q[0].x, Q[0].y, Q[0].z, Q[0].w,
                          Q[1].x, Q[1].y, Q[1].z, Q[1].w,
                          Q[2].x, Q[2].y, Q[2].z, Q[2].w,
                          Q[3].x, Q[3].y, Q[3].z, Q[3].w};
    float a[kH1];
#pragma unroll
    for (int h = 0; h < kH1; ++h) {
        float acc = W.bias1[h];
#pragma unroll
        for (int f = 0; f < kF; ++f) acc = fmaf(xv[f], W.w1[h][f], acc);
#pragma unroll
        for (int j = 0; j < kH1; ++j) acc = fmaf(h1[j], W.whh1[h][j], acc);
        a[h] = acc;
    }
#pragma unroll
    for (int h = 0; h < kH1; ++h) h1[h] = fast_tanh(a[h]);

    float c2[kH2];
#pragma unroll
    for (int m = 0; m < kH2; ++m) {
        float acc = W.bias2[m];
#pragma unroll
        for (int j = 0; j < kH1; ++j) acc = fmaf(h1[j], W.wih2[m][j], acc);
#pragma unroll
        for (int j = 0; j < kH2; ++j) acc = fmaf(h2[j], W.whh2[m][j], acc);
        c2[m] = acc;
    }
#pragma unroll
    for (int m = 0; m < kH2; ++m) h2[m] = fast_tanh(c2[m]);
}
}  // namespace

__global__ __launch_bounds__(32) void rnn_fused(
    const float* __restrict__ x,      // [B,T,F]
    const float* __restrict__ W_ih1,  // [H1,F]
    const float* __restrict__ W_hh1,  // [H1,H1]
    const float* __restrict__ b_ih1,  // [H1]
    const float* __restrict__ b_hh1,  // [H1]
    const float* __restrict__ W_ih2,  // [H2,H1]
    const float* __restrict__ W_hh2,  // [H2,H2]
    const float* __restrict__ b_ih2,  // [H2]
    const float* __restrict__ b_hh2,  // [H2]
    const float* __restrict__ W_fc,   // [1,H2]
    const float* __restrict__ b_fc,   // [1]
    float* __restrict__ out)          // [B]
{
    const int b = blockIdx.x * 32 + threadIdx.x;

    // ---- weights -> registers (wave-uniform: scalar loads / broadcast) ----
    Weights W;
#pragma unroll
    for (int h = 0; h < kH1; ++h) {
        W.bias1[h] = b_ih1[h] + b_hh1[h];
#pragma unroll
        for (int f = 0; f < kF; ++f) W.w1[h][f] = W_ih1[h * kF + f];
#pragma unroll
        for (int j = 0; j < kH1; ++j) W.whh1[h][j] = W_hh1[h * kH1 + j];
    }
#pragma unroll
    for (int m = 0; m < kH2; ++m) {
        W.bias2[m] = b_ih2[m] + b_hh2[m];
        W.wfc[m]   = W_fc[m];
#pragma unroll
        for (int j = 0; j < kH1; ++j) W.wih2[m][j] = W_ih2[m * kH1 + j];
#pragma unroll
        for (int j = 0; j < kH2; ++j) W.whh2[m][j] = W_hh2[m * kH2 + j];
    }
    W.bfc = b_fc[0];

    const float4* __restrict__ xb =
        reinterpret_cast<const float4*>(x) + (size_t)b * (kT * 4);

    float h1[kH1] = {0.f, 0.f, 0.f, 0.f, 0.f};
    float h2[kH2] = {0.f, 0.f, 0.f};

    // 4 rotating x buffers; all indices compile-time constant.
    float4 P[4][4];

    // prologue: t=0,1,2 in flight (depth 3)
    load_q(xb, 0, P[0]);
    load_q(xb, 1, P[1]);
    load_q(xb, 2, P[2]);

    for (int t = 0; t < kT; t += 4) {
        load_q(xb, t + 3, P[3]);
        do_step(P[0], W, h1, h2);
        load_q(xb, t + 4, P[0]);
        do_step(P[1], W, h1, h2);
        load_q(xb, t + 5, P[1]);
        do_step(P[2], W, h1, h2);
        load_q(xb, t + 6, P[2]);
        do_step(P[3], W, h1, h2);
    }

    float z = W.bfc;
#pragma unroll
    for (int m = 0; m < kH2; ++m) z = fmaf(h2[m], W.wfc[m], z);

    // sigmoid (harness-proven spelling)
    out[b] = __fdividef(1.0f, 1.0f + __expf(-z));
}

extern "C" void kernel_launch(void* const* d_in, const int* in_sizes, int n_in,
                              void* d_out, int out_size, void* d_ws, size_t ws_size,
                              hipStream_t stream) {
    const float* x     = (const float*)d_in[0];
    const float* W_ih1 = (const float*)d_in[1];
    const float* W_hh1 = (const float*)d_in[2];
    const float* b_ih1 = (const float*)d_in[3];
    const float* b_hh1 = (const float*)d_in[4];
    const float* W_ih2 = (const float*)d_in[5];
    const float* W_hh2 = (const float*)d_in[6];
    const float* b_ih2 = (const float*)d_in[7];
    const float* b_hh2 = (const float*)d_in[8];
    const float* W_fc  = (const float*)d_in[9];
    const float* b_fc  = (const float*)d_in[10];
    float* out = (float*)d_out;

    // 256 blocks x 32 threads: one wave on every CU.
    rnn_fused<<<dim3(kB / 32), dim3(32), 0, stream>>>(
        x, W_ih1, W_hh1, b_ih1, b_hh1, W_ih2, W_hh2, b_ih2, b_hh2, W_fc, b_fc,
        out);
}

// Round 14
// 633.959 us; speedup vs baseline: 1.4347x; 1.4347x over previous
//
#include <hip/hip_runtime.h>

// MultiFeatureRNNModel: 2-layer tanh RNN (H1=5,H2=3), B=8192, T=512, F=16,
// final-step FC(3->1)+sigmoid.
//
// r11 evidence: per-lane-contiguous-64B reads (p1, fused) run at ~2.3TB/s and
// stall-dominate; lane-consecutive (coalesced) loads (p2's xp) don't.
// r12: p1 rewritten 4-lane-cooperative so every load instr is 64 consecutive
// float4s (16 fully-used lines/instr). p2 byte-identical control (189us).
//   p1 predict: 55-85us, FETCH~268MB, WRITE~84-130MB.
//   p2 predict: 185-192us (unchanged).

namespace {
constexpr int kB  = 8192;
constexpr int kT  = 512;
constexpr int kF  = 16;
constexpr int kH1 = 5;
constexpr int kH2 = 3;

constexpr int CH = 8;                  // phase-2 chunk (double-buffered)

// float4 with 4-byte alignment (xp rows are 20B-strided, not 16B-aligned)
typedef float v4 __attribute__((ext_vector_type(4), aligned(4)));

__device__ __forceinline__ float fast_tanh(float v) {
    // tanh(v) = 1 - 2/(exp(2v)+1); saturates correctly at +-1.
    float e = __expf(v + v);
    return 1.0f - __fdividef(2.0f, e + 1.0f);
}
}  // namespace

// ---------------- phase 1: input projection (coalesced, 4-lane coop) -------
// Thread g handles flat float4 index g' = i*131072+g: (b,t,fq), fq=g'&3.
// Lanes are consecutive in g' -> global_load_dwordx4 is perfectly coalesced.
// Quad {fq=0..3} covers one (b,t): partial 5-dots reduced via shfl_xor(1,2).
__global__ __launch_bounds__(256) void rnn_p1_xproj_v2(
    const float* __restrict__ x,      // [B,T,F]
    const float* __restrict__ W_ih1,  // [H1,F]
    const float* __restrict__ b_ih1,  // [H1]
    const float* __restrict__ b_hh1,  // [H1]
    float* __restrict__ xp)           // [T,B,5]
{
    const int gid = blockIdx.x * 256 + threadIdx.x;   // 0..131071
    const int fq  = gid & 3;                          // wave-invariant

    // per-lane weight slice: wsub[h][k] = W_ih1[h][fq*4+k]
    float wsub[kH1][4], bs[kH1];
#pragma unroll
    for (int h = 0; h < kH1; ++h) {
        bs[h] = b_ih1[h] + b_hh1[h];
#pragma unroll
        for (int k = 0; k < 4; ++k) wsub[h][k] = W_ih1[h * kF + fq * 4 + k];
    }

    const float4* __restrict__ x4 = reinterpret_cast<const float4*>(x);

    constexpr int NTH   = 512 * 256;                 // 131072 threads
    constexpr int NITER = (kB * kT * 4) / NTH;       // 128

    for (int i = 0; i < NITER; ++i) {
        const int g = i * NTH + gid;
        const float4 q = x4[g];                      // coalesced

        // decode (b, t): g = (b*512 + t)*4 + fq
        const int bt = g >> 2;
        const int b  = bt >> 9;          // /512
        const int t  = bt & 511;

        float p[kH1];
#pragma unroll
        for (int h = 0; h < kH1; ++h)
            p[h] = fmaf(q.x, wsub[h][0],
                   fmaf(q.y, wsub[h][1],
                   fmaf(q.z, wsub[h][2], q.w * wsub[h][3])));

        // quad butterfly reduce (lanes fq=0..3 share bt)
#pragma unroll
        for (int h = 0; h < kH1; ++h) {
            p[h] += __shfl_xor(p[h], 1);
            p[h] += __shfl_xor(p[h], 2);
        }

        float* row = xp + ((size_t)t * kB + b) * 5;
        if (fq == 0) {
            v4 o;
            o[0] = p[0] + bs[0];
            o[1] = p[1] + bs[1];
            o[2] = p[2] + bs[2];
            o[3] = p[3] + bs[3];
            *reinterpret_cast<v4*>(row) = o;
        } else if (fq == 1) {
            row[4] = p[4] + bs[4];
        }
    }
}

// ---------------- phase 2: serial scan (unchanged r8 control, 189us) -------
__global__ __launch_bounds__(64) void rnn_p2_scan(
    const float* __restrict__ xp,     // [T,B,5]
    const float* __restrict__ W_hh1,  // [H1,H1]
    const float* __restrict__ W_ih2,  // [H2,H1]
    const float* __restrict__ W_hh2,  // [H2,H2]
    const float* __restrict__ b_ih2,  // [H2]
    const float* __restrict__ b_hh2,  // [H2]
    const float* __restrict__ W_fc,   // [1,H2]
    const float* __restrict__ b_fc,   // [1]
    float* __restrict__ out)          // [B]
{
    const int b = blockIdx.x * 64 + threadIdx.x;

    float whh1[kH1][kH1];
#pragma unroll
    for (int h = 0; h < kH1; ++h)
#pragma unroll
        for (int j = 0; j < kH1; ++j) whh1[h][j] = W_hh1[h * kH1 + j];

    float wih2[kH2][kH1], whh2[kH2][kH2], bs2[kH2], wfc[kH2];
#pragma unroll
    for (int m = 0; m < kH2; ++m) {
        bs2[m] = b_ih2[m] + b_hh2[m];
        wfc[m] = W_fc[m];
#pragma unroll
        for (int j = 0; j < kH1; ++j) wih2[m][j] = W_ih2[m * kH1 + j];
#pragma unroll
        for (int j = 0; j < kH2; ++j) whh2[m][j] = W_hh2[m * kH2 + j];
    }
    const float bfc = b_fc[0];

    float h1[kH1] = {0.f, 0.f, 0.f, 0.f, 0.f};
    float h2[kH2] = {0.f, 0.f, 0.f};

    const char* basep = reinterpret_cast<const char*>(xp + (size_t)b * 5);
    constexpr size_t TSTRIDE = (size_t)kB * 5 * sizeof(float);

    v4 A4[CH]; float A1[CH];
    v4 B4[CH]; float B1[CH];

    auto LOADC = [&](v4* Q4, float* Q1, int c) {
#pragma unroll
        for (int i = 0; i < CH; ++i) {
            const float* p = reinterpret_cast<const float*>(
                basep + (size_t)(c * CH + i) * TSTRIDE);
            Q4[i] = *reinterpret_cast<const v4*>(p);
            Q1[i] = p[4];
        }
    };

    auto STEP8 = [&](const v4* Q4, const float* Q1) {
#pragma unroll
        for (int i = 0; i < CH; ++i) {
            float a[kH1];
#pragma unroll
            for (int h = 0; h < kH1; ++h) {
                float acc = (h < 4) ? Q4[i][h] : Q1[i];
#pragma unroll
                for (int j = 0; j < kH1; ++j)
                    acc = fmaf(h1[j], whh1[h][j], acc);
                a[h] = acc;
            }
#pragma unroll
            for (int h = 0; h < kH1; ++h) h1[h] = fast_tanh(a[h]);

            float c2[kH2];
#pragma unroll
            for (int m = 0; m < kH2; ++m) {
                float acc = bs2[m];
#pragma unroll
                for (int j = 0; j < kH1; ++j)
                    acc = fmaf(h1[j], wih2[m][j], acc);
#pragma unroll
                for (int j = 0; j < kH2; ++j)
                    acc = fmaf(h2[j], whh2[m][j], acc);
                c2[m] = acc;
            }
#pragma unroll
            for (int m = 0; m < kH2; ++m) h2[m] = fast_tanh(c2[m]);
        }
    };

    LOADC(A4, A1, 0);
    constexpr int NCH = kT / CH;   // 64
    for (int c = 0; c < NCH; c += 2) {
        LOADC(B4, B1, c + 1);
        STEP8(A4, A1);
        if (c + 2 < NCH) LOADC(A4, A1, c + 2);
        STEP8(B4, B1);
    }

    float z = bfc;
#pragma unroll
    for (int m = 0; m < kH2; ++m) z = fmaf(h2[m], wfc[m], z);
    out[b] = __fdividef(1.0f, 1.0f + __expf(-z));
}

extern "C" void kernel_launch(void* const* d_in, const int* in_sizes, int n_in,
                              void* d_out, int out_size, void* d_ws, size_t ws_size,
                              hipStream_t stream) {
    const float* x     = (const float*)d_in[0];
    const float* W_ih1 = (const float*)d_in[1];
    const float* W_hh1 = (const float*)d_in[2];
    const float* b_ih1 = (const float*)d_in[3];
    const float* b_hh1 = (const float*)d_in[4];
    const float* W_ih2 = (const float*)d_in[5];
    const float* W_hh2 = (const float*)d_in[6];
    const float* b_ih2 = (const float*)d_in[7];
    const float* b_hh2 = (const float*)d_in[8];
    const float* W_fc  = (const float*)d_in[9];
    const float* b_fc  = (const float*)d_in[10];
    float* out = (float*)d_out;
    float* xp  = (float*)d_ws;   // 512*8192*5*4 = 80 MiB

    rnn_p1_xproj_v2<<<dim3(512), dim3(256), 0, stream>>>(
        x, W_ih1, b_ih1, b_hh1, xp);
    rnn_p2_scan<<<dim3(128), dim3(64), 0, stream>>>(
        xp, W_hh1, W_ih2, W_hh2, b_ih2, b_hh2, W_fc, b_fc, out);
}